// Round 2
// baseline (109.220 us; speedup 1.0000x reference)
//
#include <hip/hip_runtime.h>

// Speculative-decode next-step input preparation.
// Per request r (R=8192), with T = 1+SPEC tokens:
//   a        = clamp(accepted_num[r], 1, SC)
//   base     = input_positions[r*T] + a
//   pos[j]   = base + j
//   tok[0]   = sampled_tokens[r, a-1]; tok[1..] = spec_tokens[r, j-1]
//   blk      = block_table[r, pos/block_size]
//   slot     = blk*block_size + pos%block_size
//   seq_len  = pos + 1
// Outputs concatenated flat: [tokens | pos | seq_lens | slots], each R*T int32.
//
// Traffic model: ~1 MB write + ~1-2 MB effective read => launch-latency bound.

__global__ __launch_bounds__(256) void spec_prep_kernel(
    const int* __restrict__ input_positions,   // [R*T]
    const int* __restrict__ sampled_tokens,    // [R*SC]
    const int* __restrict__ block_table,       // [R*MAXB]
    const int* __restrict__ spec_tokens,       // [R*SPEC]
    const int* __restrict__ accepted_num,      // [R]
    const int* __restrict__ block_size_p,      // [1]
    int* __restrict__ out,                     // [4*N]
    int T, int SC, int SPEC, int MAXB, int N)
{
    int idx = blockIdx.x * blockDim.x + threadIdx.x;
    if (idx >= N) return;

    int r = idx / T;            // T==8 -> compiler emits shift
    int j = idx - r * T;

    int bs = *block_size_p;     // scalar, L2-broadcast

    int a = accepted_num[r];
    a = a < 1 ? 1 : (a > SC ? SC : a);

    int prev_base = input_positions[r * T];   // first input position of prev step
    int pos = prev_base + a + j;

    int tok = (j == 0) ? sampled_tokens[r * SC + (a - 1)]
                       : spec_tokens[r * SPEC + (j - 1)];

    int blk = block_table[r * MAXB + pos / bs];
    int slot = blk * bs + pos % bs;

    out[idx]         = tok;      // out_tokens
    out[N + idx]     = pos;      // positions
    out[2 * N + idx] = pos + 1;  // seq_lens
    out[3 * N + idx] = slot;     // slot_mapping
}

extern "C" void kernel_launch(void* const* d_in, const int* in_sizes, int n_in,
                              void* d_out, int out_size, void* d_ws, size_t ws_size,
                              hipStream_t stream) {
    // setup_inputs() order:
    // 0 input_tokens [R*T] (unused), 1 sampled_tokens [R*SC], 2 input_positions [R*T],
    // 3 seq_lens [R] (unused), 4 slot_mapping [R*T] (unused), 5 block_table [R*MAXB],
    // 6 spec_tokens [R*SPEC], 7 accepted_num [R], 8 num_seqs, 9 num_queries, 10 block_size
    const int* sampled_tokens  = (const int*)d_in[1];
    const int* input_positions = (const int*)d_in[2];
    const int* block_table     = (const int*)d_in[5];
    const int* spec_tokens     = (const int*)d_in[6];
    const int* accepted_num    = (const int*)d_in[7];
    const int* block_size_p    = (const int*)d_in[10];

    const int R    = in_sizes[7];
    const int N    = in_sizes[2];          // R*T
    const int T    = N / R;
    const int SC   = in_sizes[1] / R;
    const int SPEC = in_sizes[6] / R;
    const int MAXB = in_sizes[5] / R;

    int* out = (int*)d_out;

    const int block = 256;
    const int grid = (N + block - 1) / block;
    spec_prep_kernel<<<grid, block, 0, stream>>>(
        input_positions, sampled_tokens, block_table, spec_tokens,
        accepted_num, block_size_p, out, T, SC, SPEC, MAXB, N);
}

// Round 3
// 108.957 us; speedup vs baseline: 1.0024x; 1.0024x over previous
//
#include <hip/hip_runtime.h>

// Speculative-decode next-step input preparation — 1 thread per request.
// Per request r (R=8192), T = 1+SPEC = 8 tokens:
//   a        = clamp(accepted_num[r], 1, SC)
//   base     = input_positions[r*T] + a
//   pos[j]   = base + j
//   tok[0]   = sampled_tokens[r, a-1]; tok[j>0] = spec_tokens[r, j-1]
//   blk      = block_table[r, pos/block_size]   (pos spans <= 2 blocks)
//   slot     = blk*block_size + pos%block_size
//   seq_len  = pos + 1
// Outputs concatenated flat: [tokens | pos | seq_lens | slots], each R*T int32.
//
// Fast path: T==8 -> all 4 outputs stored as int4 pairs (dwordx4), 2 block
// table gathers per request. Generic fallback kernel for other shapes.

__global__ __launch_bounds__(256) void spec_prep_t8_kernel(
    const int* __restrict__ input_positions,   // [R*8]
    const int* __restrict__ sampled_tokens,    // [R*SC]
    const int* __restrict__ block_table,       // [R*MAXB]
    const int* __restrict__ spec_tokens,       // [R*7]
    const int* __restrict__ accepted_num,      // [R]
    const int* __restrict__ block_size_p,      // [1]
    int* __restrict__ out,                     // [4*N]
    int SC, int MAXB, int R, int N)
{
    int r = blockIdx.x * blockDim.x + threadIdx.x;
    if (r >= R) return;

    const int bs = *block_size_p;

    int a = accepted_num[r];
    a = a < 1 ? 1 : (a > SC ? SC : a);

    const int base = input_positions[r * 8] + a;   // pos of new first token

    // tokens: [sampled_tokens[r,a-1], spec_tokens[r,0..6]]
    int tok[8];
    tok[0] = sampled_tokens[r * SC + (a - 1)];
    const int* sp = spec_tokens + r * 7;
    #pragma unroll
    for (int j = 0; j < 7; ++j) tok[j + 1] = sp[j];

    // block table: positions base..base+7 span at most 2 distinct blocks
    const int d0 = base / bs;
    const int d7 = (base + 7) / bs;
    const int* btr = block_table + (long)r * MAXB;
    const int b0 = btr[d0];
    const int b1 = (d7 == d0) ? b0 : btr[d7];

    int pos[8], slot[8];
    #pragma unroll
    for (int j = 0; j < 8; ++j) {
        pos[j] = base + j;
        const int d = pos[j] / bs;
        const int blk = (d == d0) ? b0 : b1;
        slot[j] = blk * bs + (pos[j] - d * bs);
    }

    // vectorized stores: each section base is 16B-aligned; r*8*4 = 32r bytes
    int4* o_tok  = (int4*)(out) + r * 2;
    int4* o_pos  = (int4*)(out + N) + r * 2;
    int4* o_seq  = (int4*)(out + 2 * N) + r * 2;
    int4* o_slot = (int4*)(out + 3 * N) + r * 2;

    o_tok[0]  = make_int4(tok[0], tok[1], tok[2], tok[3]);
    o_tok[1]  = make_int4(tok[4], tok[5], tok[6], tok[7]);
    o_pos[0]  = make_int4(pos[0], pos[1], pos[2], pos[3]);
    o_pos[1]  = make_int4(pos[4], pos[5], pos[6], pos[7]);
    o_seq[0]  = make_int4(pos[0] + 1, pos[1] + 1, pos[2] + 1, pos[3] + 1);
    o_seq[1]  = make_int4(pos[4] + 1, pos[5] + 1, pos[6] + 1, pos[7] + 1);
    o_slot[0] = make_int4(slot[0], slot[1], slot[2], slot[3]);
    o_slot[1] = make_int4(slot[4], slot[5], slot[6], slot[7]);
}

// Generic fallback (any T): 1 thread per output element.
__global__ __launch_bounds__(256) void spec_prep_generic_kernel(
    const int* __restrict__ input_positions,
    const int* __restrict__ sampled_tokens,
    const int* __restrict__ block_table,
    const int* __restrict__ spec_tokens,
    const int* __restrict__ accepted_num,
    const int* __restrict__ block_size_p,
    int* __restrict__ out,
    int T, int SC, int SPEC, int MAXB, int N)
{
    int idx = blockIdx.x * blockDim.x + threadIdx.x;
    if (idx >= N) return;
    int r = idx / T;
    int j = idx - r * T;
    int bs = *block_size_p;
    int a = accepted_num[r];
    a = a < 1 ? 1 : (a > SC ? SC : a);
    int pos = input_positions[r * T] + a + j;
    int tok = (j == 0) ? sampled_tokens[r * SC + (a - 1)]
                       : spec_tokens[r * SPEC + (j - 1)];
    int blk = block_table[(long)r * MAXB + pos / bs];
    out[idx]         = tok;
    out[N + idx]     = pos;
    out[2 * N + idx] = pos + 1;
    out[3 * N + idx] = blk * bs + pos % bs;
}

extern "C" void kernel_launch(void* const* d_in, const int* in_sizes, int n_in,
                              void* d_out, int out_size, void* d_ws, size_t ws_size,
                              hipStream_t stream) {
    // setup_inputs() order:
    // 0 input_tokens (unused), 1 sampled_tokens [R*SC], 2 input_positions [R*T],
    // 3 seq_lens (unused), 4 slot_mapping (unused), 5 block_table [R*MAXB],
    // 6 spec_tokens [R*SPEC], 7 accepted_num [R], 8 num_seqs, 9 num_queries, 10 block_size
    const int* sampled_tokens  = (const int*)d_in[1];
    const int* input_positions = (const int*)d_in[2];
    const int* block_table     = (const int*)d_in[5];
    const int* spec_tokens     = (const int*)d_in[6];
    const int* accepted_num    = (const int*)d_in[7];
    const int* block_size_p    = (const int*)d_in[10];

    const int R    = in_sizes[7];
    const int N    = in_sizes[2];          // R*T
    const int T    = N / R;
    const int SC   = in_sizes[1] / R;
    const int SPEC = in_sizes[6] / R;
    const int MAXB = in_sizes[5] / R;

    int* out = (int*)d_out;

    if (T == 8 && SPEC == 7) {
        const int block = 256;
        const int grid = (R + block - 1) / block;   // 32 workgroups
        spec_prep_t8_kernel<<<grid, block, 0, stream>>>(
            input_positions, sampled_tokens, block_table, spec_tokens,
            accepted_num, block_size_p, out, SC, MAXB, R, N);
    } else {
        const int block = 256;
        const int grid = (N + block - 1) / block;
        spec_prep_generic_kernel<<<grid, block, 0, stream>>>(
            input_positions, sampled_tokens, block_table, spec_tokens,
            accepted_num, block_size_p, out, T, SC, SPEC, MAXB, N);
    }
}